// Round 1
// baseline (787.971 us; speedup 1.0000x reference)
//
#include <hip/hip_runtime.h>
#include <cstddef>

// ContextWindowAttention: B=8192 windows, N=49 tokens, C=128, H=4, D=32.
// One block per window, 4 waves (wave=M-tile in proj phases, wave=head in attn).
// bf16 MFMA 16x16x32 everywhere; fp32 softmax in registers; 64 KB LDS, 2 blocks/CU.

#define MFMA16 __builtin_amdgcn_mfma_f32_16x16x32_bf16

typedef float f32x4 __attribute__((ext_vector_type(4)));
typedef __bf16 bf16x8 __attribute__((ext_vector_type(8)));
typedef unsigned short u16x8 __attribute__((ext_vector_type(8)));

constexpr int NTOK = 49;
constexpr int CDIM = 128;
constexpr int NWIN = 1024;
constexpr int NB = 8192;
constexpr float SCALE_F = 0.17677669529663687f;  // 32^-0.5

__device__ __forceinline__ unsigned short f2bf(float f) {
  unsigned int u = __builtin_bit_cast(unsigned int, f);
  u += 0x7FFFu + ((u >> 16) & 1u);  // RNE
  return (unsigned short)(u >> 16);
}

// Swizzled byte offsets: 8-elem (16 B) blocks XORed with row to avoid bank conflicts.
__device__ __forceinline__ int sw128(int row, int col) {  // [rows][128] bf16
  return (row << 8) + ((((col >> 3) ^ row) & 15) << 4) + ((col & 7) << 1);
}
__device__ __forceinline__ int sw64(int row, int col) {  // [rows][64] bf16
  return (row << 7) + ((((col >> 3) ^ (row >> 1)) & 7) << 4) + ((col & 7) << 1);
}

// ---------------- prepack: weights -> bf16 transposed, bias gather ----------------
__global__ void prepack_kernel(const float* __restrict__ Wq, const float* __restrict__ Wkv,
                               const float* __restrict__ Wp, const float* __restrict__ bias_table,
                               const int* __restrict__ rel_idx,
                               unsigned short* __restrict__ wWq, unsigned short* __restrict__ wWk,
                               unsigned short* __restrict__ wWv, unsigned short* __restrict__ wWp,
                               float* __restrict__ wBias) {
  int t = blockIdx.x * 256 + threadIdx.x;  // 0..16383
  int n = t >> 7, k = t & 127;             // W_t[n][k] = W[k][n]
  wWq[t] = f2bf(Wq[k * 128 + n]);
  wWk[t] = f2bf(Wkv[k * 256 + n]);         // K channels = cols 0..127  (h*32+d)
  wWv[t] = f2bf(Wkv[k * 256 + 128 + n]);   // V channels = cols 128..255
  wWp[t] = f2bf(Wp[k * 128 + n]);
  if (t < 2401) {
    int r = rel_idx[t];
#pragma unroll
    for (int h = 0; h < 4; ++h) wBias[h * 2401 + t] = bias_table[r * 4 + h];
  }
}

// ---------------- main kernel helpers ----------------
// Stage one 64x128 bf16 weight half into LDS @49152 with sw128 block swizzle.
__device__ __forceinline__ void stage_w(unsigned char* lds, const unsigned short* __restrict__ wsrc,
                                        int half, int tid) {
  const uint4* src = (const uint4*)(wsrc + half * 8192);
  uint4* dst = (uint4*)(lds + 49152);
#pragma unroll
  for (int it = 0; it < 4; ++it) {
    int i = tid + it * 256;  // 16B-block index, 0..1023
    int lr = i >> 4;
    dst[(lr << 4) | ((i ^ lr) & 15)] = src[i];
  }
}

// Projection: 4 out-tiles (this wave's M-tile x N-tiles of current weight half).
// TGT: 0 -> Qs(@0), 1 -> Ks(@16384), 2 -> Vt transposed (@32768)
template <int TGT>
__device__ __forceinline__ void p1_compute(unsigned char* lds, const bf16x8 af[4],
                                           const float* __restrict__ biasv, int half, int w,
                                           int li, int q4) {
#pragma unroll
  for (int ntl = 0; ntl < 4; ++ntl) {
    f32x4 acc = {0.f, 0.f, 0.f, 0.f};
#pragma unroll
    for (int ks = 0; ks < 4; ++ks) {
      bf16x8 bfr = *(const bf16x8*)(lds + 49152 + sw128(ntl * 16 + li, ks * 32 + q4 * 8));
      acc = MFMA16(af[ks], bfr, acc, 0, 0, 0);
    }
    const int n = half * 64 + ntl * 16 + li;  // out channel 0..127
    const float bv = biasv[n];
#pragma unroll
    for (int r = 0; r < 4; ++r) {
      const int m = w * 16 + q4 * 4 + r;  // token row
      const unsigned short us = f2bf(acc[r] + bv);
      if (TGT == 0)
        *(unsigned short*)(lds + sw128(m, n)) = us;
      else if (TGT == 1)
        *(unsigned short*)(lds + 16384 + sw128(m, n)) = us;
      else
        *(unsigned short*)(lds + 32768 + sw64(n, m)) = us;  // Vt[chan][token]
    }
  }
}

__global__ __launch_bounds__(256, 2) void attn_kernel(
    const float* __restrict__ x, const float* __restrict__ y, const float* __restrict__ mask,
    const float* __restrict__ bq, const float* __restrict__ bkv, const float* __restrict__ bp,
    const unsigned short* __restrict__ wWq, const unsigned short* __restrict__ wWk,
    const unsigned short* __restrict__ wWv, const unsigned short* __restrict__ wWp,
    const float* __restrict__ wBias, float* __restrict__ out) {
  // 0..16K Qs[64][128] (later Zs), 16K..32K Ks (Qs+Ks later Ps[4][64][64]),
  // 32K..48K Vt[128][64], 48K..64K weight staging buffer.
  __shared__ __align__(16) unsigned char lds[65536];
  const int tid = threadIdx.x;
  const int w = tid >> 6;    // wave id
  const int lane = tid & 63;
  const int li = lane & 15;  // A/B frag row/col, C/D col
  const int q4 = lane >> 4;  // quad group
  const int b = blockIdx.x;

  // Preload A-fragments of X and Y for this wave's M-tile (rows w*16+li), rows>=49 zeroed.
  bf16x8 ax[4], ay[4];
  {
    const int mrow = w * 16 + li;
    const bool mv = mrow < NTOK;
    const float* xr = x + ((size_t)b * NTOK + (mv ? mrow : 0)) * CDIM;
    const float* yr = y + ((size_t)b * NTOK + (mv ? mrow : 0)) * CDIM;
#pragma unroll
    for (int ks = 0; ks < 4; ++ks) {
      const int c0 = ks * 32 + q4 * 8;
      float4 a0 = *(const float4*)(xr + c0);
      float4 a1 = *(const float4*)(xr + c0 + 4);
      float4 b0 = *(const float4*)(yr + c0);
      float4 b1 = *(const float4*)(yr + c0 + 4);
      if (!mv) {
        a0.x = a0.y = a0.z = a0.w = 0.f; a1.x = a1.y = a1.z = a1.w = 0.f;
        b0.x = b0.y = b0.z = b0.w = 0.f; b1.x = b1.y = b1.z = b1.w = 0.f;
      }
      u16x8 ta, tb;
      ta[0] = f2bf(a0.x); ta[1] = f2bf(a0.y); ta[2] = f2bf(a0.z); ta[3] = f2bf(a0.w);
      ta[4] = f2bf(a1.x); ta[5] = f2bf(a1.y); ta[6] = f2bf(a1.z); ta[7] = f2bf(a1.w);
      tb[0] = f2bf(b0.x); tb[1] = f2bf(b0.y); tb[2] = f2bf(b0.z); tb[3] = f2bf(b0.w);
      tb[4] = f2bf(b1.x); tb[5] = f2bf(b1.y); tb[6] = f2bf(b1.z); tb[7] = f2bf(b1.w);
      ax[ks] = __builtin_bit_cast(bf16x8, ta);
      ay[ks] = __builtin_bit_cast(bf16x8, tb);
    }
  }

  // ---- Phase 1: Q/K/V projections (weight halves staged through 16 KB buffer) ----
  stage_w(lds, wWq, 0, tid); __syncthreads();
  p1_compute<0>(lds, ax, bq, 0, w, li, q4); __syncthreads();
  stage_w(lds, wWq, 1, tid); __syncthreads();
  p1_compute<0>(lds, ax, bq, 1, w, li, q4); __syncthreads();
  stage_w(lds, wWk, 0, tid); __syncthreads();
  p1_compute<1>(lds, ay, bkv, 0, w, li, q4); __syncthreads();
  stage_w(lds, wWk, 1, tid); __syncthreads();
  p1_compute<1>(lds, ay, bkv, 1, w, li, q4); __syncthreads();
  stage_w(lds, wWv, 0, tid); __syncthreads();
  p1_compute<2>(lds, ay, bkv + 128, 0, w, li, q4); __syncthreads();
  stage_w(lds, wWv, 1, tid); __syncthreads();
  p1_compute<2>(lds, ay, bkv + 128, 1, w, li, q4); __syncthreads();

  // ---- Phase 2a: wave = head. S = SCALE*(Q Kt) + bias + mask, softmax in regs ----
  const int h = w;
  const int PS = h * 8192;  // P buffer aliases Qs+Ks after barrier
  f32x4 s[4][4];
  {
    bf16x8 aq[4], bk[4];
#pragma unroll
    for (int mt = 0; mt < 4; ++mt)
      aq[mt] = *(const bf16x8*)(lds + sw128(mt * 16 + li, h * 32 + q4 * 8));
#pragma unroll
    for (int nt = 0; nt < 4; ++nt)
      bk[nt] = *(const bf16x8*)(lds + 16384 + sw128(nt * 16 + li, h * 32 + q4 * 8));
    const f32x4 zz = {0.f, 0.f, 0.f, 0.f};
#pragma unroll
    for (int mt = 0; mt < 4; ++mt)
#pragma unroll
      for (int nt = 0; nt < 4; ++nt) s[mt][nt] = MFMA16(aq[mt], bk[nt], zz, 0, 0, 0);
  }
  const float* __restrict__ maskw = mask + (size_t)(b & (NWIN - 1)) * 2401;
  const float* __restrict__ biash = wBias + h * 2401;
#pragma unroll
  for (int mt = 0; mt < 4; ++mt) {
#pragma unroll
    for (int r = 0; r < 4; ++r) {
      const int m = mt * 16 + q4 * 4 + r;
      const bool mvld = m < NTOK;
      const int mo = (mvld ? m : 0) * NTOK;
      float vv[4];
#pragma unroll
      for (int nt = 0; nt < 4; ++nt) {
        const int n = nt * 16 + li;
        float t = SCALE_F * s[mt][nt][r];
        if (n < NTOK) {
          if (mvld) t += biash[mo + n] + maskw[mo + n];
        } else {
          t = -1e30f;  // pad cols excluded from softmax
        }
        vv[nt] = t;
      }
      // row's 64 cols live in this 16-lane group (4 per lane)
      float mx = fmaxf(fmaxf(vv[0], vv[1]), fmaxf(vv[2], vv[3]));
      mx = fmaxf(mx, __shfl_xor(mx, 1, 16));
      mx = fmaxf(mx, __shfl_xor(mx, 2, 16));
      mx = fmaxf(mx, __shfl_xor(mx, 4, 16));
      mx = fmaxf(mx, __shfl_xor(mx, 8, 16));
      float sm = 0.f;
#pragma unroll
      for (int nt = 0; nt < 4; ++nt) {
        vv[nt] = __expf(vv[nt] - mx);
        sm += vv[nt];
      }
      sm += __shfl_xor(sm, 1, 16);
      sm += __shfl_xor(sm, 2, 16);
      sm += __shfl_xor(sm, 4, 16);
      sm += __shfl_xor(sm, 8, 16);
      const float inv = __builtin_amdgcn_rcpf(sm);
#pragma unroll
      for (int nt = 0; nt < 4; ++nt) s[mt][nt][r] = vv[nt] * inv;
    }
  }
  __syncthreads();  // all waves done reading Qs/Ks -> safe to overwrite with P
#pragma unroll
  for (int mt = 0; mt < 4; ++mt)
#pragma unroll
    for (int r = 0; r < 4; ++r) {
      const int m = mt * 16 + q4 * 4 + r;
#pragma unroll
      for (int nt = 0; nt < 4; ++nt)
        *(unsigned short*)(lds + PS + sw64(m, nt * 16 + li)) = f2bf(s[mt][nt][r]);
    }

  // ---- Phase 2b: O = P V (C/D->A layout via LDS round trip, per-wave, no barrier) ----
  f32x4 o[4][2];
  {
    bf16x8 ap[4][2], bv2[2][2];
#pragma unroll
    for (int mt = 0; mt < 4; ++mt)
#pragma unroll
      for (int ks = 0; ks < 2; ++ks)
        ap[mt][ks] = *(const bf16x8*)(lds + PS + sw64(mt * 16 + li, ks * 32 + q4 * 8));
#pragma unroll
    for (int nti = 0; nti < 2; ++nti)
#pragma unroll
      for (int ks = 0; ks < 2; ++ks)
        bv2[nti][ks] =
            *(const bf16x8*)(lds + 32768 + sw64(h * 32 + nti * 16 + li, ks * 32 + q4 * 8));
#pragma unroll
    for (int mt = 0; mt < 4; ++mt)
#pragma unroll
      for (int nti = 0; nti < 2; ++nti) {
        f32x4 acc = {0.f, 0.f, 0.f, 0.f};
#pragma unroll
        for (int ks = 0; ks < 2; ++ks) acc = MFMA16(ap[mt][ks], bv2[nti][ks], acc, 0, 0, 0);
        o[mt][nti] = acc;
      }
  }
  __syncthreads();  // all waves done reading P -> safe to overwrite with Z

  // write Z[64][128] (@0, aliases P heads 0-1) and stage Wp half 0
#pragma unroll
  for (int mt = 0; mt < 4; ++mt)
#pragma unroll
    for (int nti = 0; nti < 2; ++nti)
#pragma unroll
      for (int r = 0; r < 4; ++r) {
        const int m = mt * 16 + q4 * 4 + r;
        const int c = h * 32 + nti * 16 + li;
        *(unsigned short*)(lds + sw128(m, c)) = f2bf(o[mt][nti][r]);
      }
  stage_w(lds, wWp, 0, tid);
  __syncthreads();

  // ---- Phase 3: out = Z @ Wp_t + bp ----
  bf16x8 az[4];
#pragma unroll
  for (int ks = 0; ks < 4; ++ks)
    az[ks] = *(const bf16x8*)(lds + sw128(w * 16 + li, ks * 32 + q4 * 8));
#pragma unroll
  for (int half = 0; half < 2; ++half) {
    if (half == 1) {
      __syncthreads();
      stage_w(lds, wWp, 1, tid);
      __syncthreads();
    }
#pragma unroll
    for (int ntl = 0; ntl < 4; ++ntl) {
      f32x4 acc = {0.f, 0.f, 0.f, 0.f};
#pragma unroll
      for (int ks = 0; ks < 4; ++ks) {
        bf16x8 bw = *(const bf16x8*)(lds + 49152 + sw128(ntl * 16 + li, ks * 32 + q4 * 8));
        acc = MFMA16(az[ks], bw, acc, 0, 0, 0);
      }
      const int n = half * 64 + ntl * 16 + li;
      const float bpv = bp[n];
#pragma unroll
      for (int r = 0; r < 4; ++r) {
        const int m = w * 16 + q4 * 4 + r;
        if (m < NTOK) out[((size_t)b * NTOK + m) * CDIM + n] = acc[r] + bpv;
      }
    }
  }
}

extern "C" void kernel_launch(void* const* d_in, const int* in_sizes, int n_in, void* d_out,
                              int out_size, void* d_ws, size_t ws_size, hipStream_t stream) {
  const float* x = (const float*)d_in[0];
  const float* y = (const float*)d_in[1];
  const float* mask = (const float*)d_in[2];
  const float* Wq = (const float*)d_in[3];
  const float* bq = (const float*)d_in[4];
  const float* Wkv = (const float*)d_in[5];
  const float* bkv = (const float*)d_in[6];
  const float* bt = (const float*)d_in[7];
  const float* Wp = (const float*)d_in[8];
  const float* bp = (const float*)d_in[9];
  const int* rel = (const int*)d_in[10];
  float* out = (float*)d_out;

  // ws layout: 4x 16384 bf16 transposed weights (128 KB) + [H][49][49] fp32 bias (150 KB)
  unsigned short* wWq = (unsigned short*)d_ws;
  unsigned short* wWk = wWq + 16384;
  unsigned short* wWv = wWq + 32768;
  unsigned short* wWp = wWq + 49152;
  float* wBias = (float*)((char*)d_ws + 131072);

  prepack_kernel<<<64, 256, 0, stream>>>(Wq, Wkv, Wp, bt, rel, wWq, wWk, wWv, wWp, wBias);
  attn_kernel<<<NB, 256, 0, stream>>>(x, y, mask, bq, bkv, bp, wWq, wWk, wWv, wWp, wBias, out);
}

// Round 2
// 752.172 us; speedup vs baseline: 1.0476x; 1.0476x over previous
//
#include <hip/hip_runtime.h>
#include <cstddef>

// ContextWindowAttention: B=8192 windows, N=49 tokens, C=128, H=4, D=32.
// One block per window, 4 waves. Weights prepacked in MFMA B-fragment order and
// loaded global->VGPR (L2 broadcast) -- no LDS staging, 4 barriers total.
// LDS 48 KB -> 3 blocks/CU. bf16 MFMA 16x16x32 everywhere; fp32 softmax in regs.

#define MFMA16 __builtin_amdgcn_mfma_f32_16x16x32_bf16

typedef float f32x4 __attribute__((ext_vector_type(4)));
typedef __bf16 bf16x8 __attribute__((ext_vector_type(8)));
typedef unsigned short u16x8 __attribute__((ext_vector_type(8)));

constexpr int NTOK = 49;
constexpr int CDIM = 128;
constexpr int NWIN = 1024;
constexpr int NB = 8192;
constexpr float SCALE_F = 0.17677669529663687f;  // 32^-0.5

__device__ __forceinline__ unsigned short f2bf(float f) {
  unsigned int u = __builtin_bit_cast(unsigned int, f);
  u += 0x7FFFu + ((u >> 16) & 1u);  // RNE
  return (unsigned short)(u >> 16);
}

// Swizzled byte offsets: 8-elem (16 B) blocks XORed with row to avoid bank conflicts.
__device__ __forceinline__ int sw128(int row, int col) {  // [rows][128] bf16
  return (row << 8) + ((((col >> 3) ^ row) & 15) << 4) + ((col & 7) << 1);
}
__device__ __forceinline__ int sw64(int row, int col) {  // [rows][64] bf16
  return (row << 7) + ((((col >> 3) ^ (row >> 1)) & 7) << 4) + ((col & 7) << 1);
}

// ---------------- prepack: weights -> bf16 B-fragment order, bias gather ----------------
// wFrag layout: [mat(4)][frag(32)][lane(64)][8] bf16, frag = nt*4+ks.
// Fragment element j of lane (q4,li): W[k = ks*32+q4*8+j][n = nt*16+li].
// mat: 0=Wq, 1=Wk (Wkv cols 0..127), 2=Wv (Wkv cols 128..255), 3=Wp.
__global__ void prepack_kernel(const float* __restrict__ Wq, const float* __restrict__ Wkv,
                               const float* __restrict__ Wp, const float* __restrict__ bias_table,
                               const int* __restrict__ rel_idx,
                               unsigned short* __restrict__ wFrag, float* __restrict__ wBias) {
  int t = blockIdx.x * 256 + threadIdx.x;  // 0..16383
  if (t < 8192) {
    const int mat = t >> 11;  // 0..3
    const int g = t & 2047;
    const int frag = g >> 6, lane = g & 63;
    const int nt = frag >> 2, ks = frag & 3;
    const int li = lane & 15, q4 = lane >> 4;
    const int n = nt * 16 + li;
    u16x8 tmp;
#pragma unroll
    for (int j = 0; j < 8; ++j) {
      const int k = ks * 32 + q4 * 8 + j;
      float v;
      if (mat == 0) v = Wq[k * 128 + n];
      else if (mat == 1) v = Wkv[k * 256 + n];
      else if (mat == 2) v = Wkv[k * 256 + 128 + n];
      else v = Wp[k * 128 + n];
      tmp[j] = f2bf(v);
    }
    *(u16x8*)(wFrag + (size_t)t * 8) = tmp;  // = mat*16384 + frag*512 + lane*8
  } else {
    const int tb = t - 8192;
    if (tb < 2401) {
      const int r = rel_idx[tb];
#pragma unroll
      for (int h = 0; h < 4; ++h) wBias[h * 2401 + tb] = bias_table[r * 4 + h];
    }
  }
}

__global__ __launch_bounds__(256, 3) void attn_kernel(
    const float* __restrict__ x, const float* __restrict__ y, const float* __restrict__ mask,
    const float* __restrict__ bq, const float* __restrict__ bkv, const float* __restrict__ bp,
    const unsigned short* __restrict__ wFrag, const float* __restrict__ wBias,
    float* __restrict__ out) {
  // 0..16K Qs[64][128], 16K..32K Ks[64][128], 32K..48K Vt[128][64].
  // After barrier#2: Ps[4][64][64] aliases Qs+Ks (head h at h*8192).
  // After barrier#3: Zs[64][128] aliases 0..16K.
  __shared__ __align__(16) unsigned char lds[49152];
  const int tid = threadIdx.x;
  const int w = tid >> 6;
  const int lane = tid & 63;
  const int li = lane & 15;
  const int q4 = lane >> 4;
  const int b = blockIdx.x;
  const int mh = w >> 1;  // M-half (rows 32*mh .. 32*mh+31)
  const int nh = w & 1;   // N-half (cols 64*nh .. 64*nh+63)

  // ---- Load A-fragments of X and Y for this wave's 2 M-tiles (rows >= 49 zeroed) ----
  bf16x8 ax[2][4], ay[2][4];
#pragma unroll
  for (int t = 0; t < 2; ++t) {
    const int mrow = mh * 32 + t * 16 + li;
    const bool mv = mrow < NTOK;
    const float* xr = x + ((size_t)b * NTOK + (mv ? mrow : 0)) * CDIM;
    const float* yr = y + ((size_t)b * NTOK + (mv ? mrow : 0)) * CDIM;
#pragma unroll
    for (int ks = 0; ks < 4; ++ks) {
      const int c0 = ks * 32 + q4 * 8;
      float4 a0 = *(const float4*)(xr + c0);
      float4 a1 = *(const float4*)(xr + c0 + 4);
      float4 b0 = *(const float4*)(yr + c0);
      float4 b1 = *(const float4*)(yr + c0 + 4);
      if (!mv) {
        a0.x = a0.y = a0.z = a0.w = 0.f; a1.x = a1.y = a1.z = a1.w = 0.f;
        b0.x = b0.y = b0.z = b0.w = 0.f; b1.x = b1.y = b1.z = b1.w = 0.f;
      }
      u16x8 ta, tb;
      ta[0] = f2bf(a0.x); ta[1] = f2bf(a0.y); ta[2] = f2bf(a0.z); ta[3] = f2bf(a0.w);
      ta[4] = f2bf(a1.x); ta[5] = f2bf(a1.y); ta[6] = f2bf(a1.z); ta[7] = f2bf(a1.w);
      tb[0] = f2bf(b0.x); tb[1] = f2bf(b0.y); tb[2] = f2bf(b0.z); tb[3] = f2bf(b0.w);
      tb[4] = f2bf(b1.x); tb[5] = f2bf(b1.y); tb[6] = f2bf(b1.z); tb[7] = f2bf(b1.w);
      ax[t][ks] = __builtin_bit_cast(bf16x8, ta);
      ay[t][ks] = __builtin_bit_cast(bf16x8, tb);
    }
  }

  // Weight fragment pointers for this wave's N-half (16 frags of 1 KB each, contiguous).
  const unsigned short* wq = wFrag + 0 * 16384 + nh * 8192;
  const unsigned short* wk = wFrag + 1 * 16384 + nh * 8192;
  const unsigned short* wv = wFrag + 2 * 16384 + nh * 8192;
  const unsigned short* wp = wFrag + 3 * 16384 + nh * 8192;

  // ---- Phase 1: Q/K/V projections, weight frags straight from global (L2) ----
#pragma unroll
  for (int ntl = 0; ntl < 4; ++ntl) {  // Q -> Qs
    bf16x8 wf[4];
#pragma unroll
    for (int ks = 0; ks < 4; ++ks)
      wf[ks] = *(const bf16x8*)(wq + (ntl * 4 + ks) * 512 + lane * 8);
    const int n = nh * 64 + ntl * 16 + li;
    const float bv = bq[n];
#pragma unroll
    for (int t = 0; t < 2; ++t) {
      f32x4 acc = {0.f, 0.f, 0.f, 0.f};
#pragma unroll
      for (int ks = 0; ks < 4; ++ks) acc = MFMA16(ax[t][ks], wf[ks], acc, 0, 0, 0);
#pragma unroll
      for (int r = 0; r < 4; ++r) {
        const int m = mh * 32 + t * 16 + q4 * 4 + r;
        *(unsigned short*)(lds + sw128(m, n)) = f2bf(acc[r] + bv);
      }
    }
  }
#pragma unroll
  for (int ntl = 0; ntl < 4; ++ntl) {  // K -> Ks
    bf16x8 wf[4];
#pragma unroll
    for (int ks = 0; ks < 4; ++ks)
      wf[ks] = *(const bf16x8*)(wk + (ntl * 4 + ks) * 512 + lane * 8);
    const int n = nh * 64 + ntl * 16 + li;
    const float bv = bkv[n];
#pragma unroll
    for (int t = 0; t < 2; ++t) {
      f32x4 acc = {0.f, 0.f, 0.f, 0.f};
#pragma unroll
      for (int ks = 0; ks < 4; ++ks) acc = MFMA16(ay[t][ks], wf[ks], acc, 0, 0, 0);
#pragma unroll
      for (int r = 0; r < 4; ++r) {
        const int m = mh * 32 + t * 16 + q4 * 4 + r;
        *(unsigned short*)(lds + 16384 + sw128(m, n)) = f2bf(acc[r] + bv);
      }
    }
  }
#pragma unroll
  for (int ntl = 0; ntl < 4; ++ntl) {  // V -> Vt (transposed [chan][token])
    bf16x8 wf[4];
#pragma unroll
    for (int ks = 0; ks < 4; ++ks)
      wf[ks] = *(const bf16x8*)(wv + (ntl * 4 + ks) * 512 + lane * 8);
    const int n = nh * 64 + ntl * 16 + li;
    const float bv = bkv[128 + n];
#pragma unroll
    for (int t = 0; t < 2; ++t) {
      f32x4 acc = {0.f, 0.f, 0.f, 0.f};
#pragma unroll
      for (int ks = 0; ks < 4; ++ks) acc = MFMA16(ay[t][ks], wf[ks], acc, 0, 0, 0);
#pragma unroll
      for (int r = 0; r < 4; ++r) {
        const int m = mh * 32 + t * 16 + q4 * 4 + r;
        *(unsigned short*)(lds + 32768 + sw64(n, m)) = f2bf(acc[r] + bv);
      }
    }
  }
  __syncthreads();  // #1: Q/K/V ready

  // ---- Phase 2a: wave = head. S = SCALE*(Q Kt) + bias + mask, softmax in regs ----
  const int h = w;
  const int PS = h * 8192;  // P region aliases Qs/Ks after barrier #2
  f32x4 s[4][4];
  {
    bf16x8 aq[4], bk[4];
#pragma unroll
    for (int mt = 0; mt < 4; ++mt)
      aq[mt] = *(const bf16x8*)(lds + sw128(mt * 16 + li, h * 32 + q4 * 8));
#pragma unroll
    for (int nt = 0; nt < 4; ++nt)
      bk[nt] = *(const bf16x8*)(lds + 16384 + sw128(nt * 16 + li, h * 32 + q4 * 8));
    const f32x4 zz = {0.f, 0.f, 0.f, 0.f};
#pragma unroll
    for (int mt = 0; mt < 4; ++mt)
#pragma unroll
      for (int nt = 0; nt < 4; ++nt) s[mt][nt] = MFMA16(aq[mt], bk[nt], zz, 0, 0, 0);
  }
  const float* __restrict__ maskw = mask + (size_t)(b & (NWIN - 1)) * 2401;
  const float* __restrict__ biash = wBias + h * 2401;
#pragma unroll
  for (int mt = 0; mt < 4; ++mt) {
#pragma unroll
    for (int r = 0; r < 4; ++r) {
      const int m = mt * 16 + q4 * 4 + r;
      const bool mvld = m < NTOK;
      const int mo = (mvld ? m : 0) * NTOK;
      float vv[4];
#pragma unroll
      for (int nt = 0; nt < 4; ++nt) {
        const int n = nt * 16 + li;
        float t = SCALE_F * s[mt][nt][r];
        if (n < NTOK) {
          if (mvld) t += biash[mo + n] + maskw[mo + n];
        } else {
          t = -1e30f;  // pad cols excluded from softmax
        }
        vv[nt] = t;
      }
      float mx = fmaxf(fmaxf(vv[0], vv[1]), fmaxf(vv[2], vv[3]));
      mx = fmaxf(mx, __shfl_xor(mx, 1, 16));
      mx = fmaxf(mx, __shfl_xor(mx, 2, 16));
      mx = fmaxf(mx, __shfl_xor(mx, 4, 16));
      mx = fmaxf(mx, __shfl_xor(mx, 8, 16));
      float sm = 0.f;
#pragma unroll
      for (int nt = 0; nt < 4; ++nt) {
        vv[nt] = __expf(vv[nt] - mx);
        sm += vv[nt];
      }
      sm += __shfl_xor(sm, 1, 16);
      sm += __shfl_xor(sm, 2, 16);
      sm += __shfl_xor(sm, 4, 16);
      sm += __shfl_xor(sm, 8, 16);
      const float inv = __builtin_amdgcn_rcpf(sm);
#pragma unroll
      for (int nt = 0; nt < 4; ++nt) s[mt][nt][r] = vv[nt] * inv;
    }
  }
  __syncthreads();  // #2: everyone done reading Qs/Ks -> safe to overwrite with P
#pragma unroll
  for (int mt = 0; mt < 4; ++mt)
#pragma unroll
    for (int r = 0; r < 4; ++r) {
      const int m = mt * 16 + q4 * 4 + r;
#pragma unroll
      for (int nt = 0; nt < 4; ++nt)
        *(unsigned short*)(lds + PS + sw64(m, nt * 16 + li)) = f2bf(s[mt][nt][r]);
    }

  // ---- Phase 2b: O = P V (per-wave LDS round trip; same-wave DS ordering) ----
  f32x4 o[4][2];
  {
    bf16x8 ap[4][2], bv2[2][2];
#pragma unroll
    for (int mt = 0; mt < 4; ++mt)
#pragma unroll
      for (int ks = 0; ks < 2; ++ks)
        ap[mt][ks] = *(const bf16x8*)(lds + PS + sw64(mt * 16 + li, ks * 32 + q4 * 8));
#pragma unroll
    for (int nti = 0; nti < 2; ++nti)
#pragma unroll
      for (int ks = 0; ks < 2; ++ks)
        bv2[nti][ks] =
            *(const bf16x8*)(lds + 32768 + sw64(h * 32 + nti * 16 + li, ks * 32 + q4 * 8));
#pragma unroll
    for (int mt = 0; mt < 4; ++mt)
#pragma unroll
      for (int nti = 0; nti < 2; ++nti) {
        f32x4 acc = {0.f, 0.f, 0.f, 0.f};
#pragma unroll
        for (int ks = 0; ks < 2; ++ks) acc = MFMA16(ap[mt][ks], bv2[nti][ks], acc, 0, 0, 0);
        o[mt][nti] = acc;
      }
  }
  __syncthreads();  // #3: all waves done reading P -> safe to overwrite with Z

  // write Z[64][128] @0 (aliases P heads 0/1)
#pragma unroll
  for (int mt = 0; mt < 4; ++mt)
#pragma unroll
    for (int nti = 0; nti < 2; ++nti)
#pragma unroll
      for (int r = 0; r < 4; ++r) {
        const int m = mt * 16 + q4 * 4 + r;
        const int c = h * 32 + nti * 16 + li;
        *(unsigned short*)(lds + sw128(m, c)) = f2bf(o[mt][nti][r]);
      }
  __syncthreads();  // #4: Z ready

  // ---- Phase 3: out = Z @ Wp_t + bp, Wp frags straight from global ----
  bf16x8 az[2][4];
#pragma unroll
  for (int t = 0; t < 2; ++t)
#pragma unroll
    for (int ks = 0; ks < 4; ++ks)
      az[t][ks] = *(const bf16x8*)(lds + sw128(mh * 32 + t * 16 + li, ks * 32 + q4 * 8));
#pragma unroll
  for (int ntl = 0; ntl < 4; ++ntl) {
    bf16x8 wf[4];
#pragma unroll
    for (int ks = 0; ks < 4; ++ks)
      wf[ks] = *(const bf16x8*)(wp + (ntl * 4 + ks) * 512 + lane * 8);
    const int n = nh * 64 + ntl * 16 + li;
    const float bpv = bp[n];
#pragma unroll
    for (int t = 0; t < 2; ++t) {
      f32x4 acc = {0.f, 0.f, 0.f, 0.f};
#pragma unroll
      for (int ks = 0; ks < 4; ++ks) acc = MFMA16(az[t][ks], wf[ks], acc, 0, 0, 0);
#pragma unroll
      for (int r = 0; r < 4; ++r) {
        const int m = mh * 32 + t * 16 + q4 * 4 + r;
        if (m < NTOK) out[((size_t)b * NTOK + m) * CDIM + n] = acc[r] + bpv;
      }
    }
  }
}

extern "C" void kernel_launch(void* const* d_in, const int* in_sizes, int n_in, void* d_out,
                              int out_size, void* d_ws, size_t ws_size, hipStream_t stream) {
  const float* x = (const float*)d_in[0];
  const float* y = (const float*)d_in[1];
  const float* mask = (const float*)d_in[2];
  const float* Wq = (const float*)d_in[3];
  const float* bq = (const float*)d_in[4];
  const float* Wkv = (const float*)d_in[5];
  const float* bkv = (const float*)d_in[6];
  const float* bt = (const float*)d_in[7];
  const float* Wp = (const float*)d_in[8];
  const float* bp = (const float*)d_in[9];
  const int* rel = (const int*)d_in[10];
  float* out = (float*)d_out;

  // ws: 4 x 16384 bf16 fragment-ordered weights (128 KB) + [H][49][49] fp32 bias
  unsigned short* wFrag = (unsigned short*)d_ws;
  float* wBias = (float*)((char*)d_ws + 131072);

  prepack_kernel<<<64, 256, 0, stream>>>(Wq, Wkv, Wp, bt, rel, wFrag, wBias);
  attn_kernel<<<NB, 256, 0, stream>>>(x, y, mask, bq, bkv, bp, wFrag, wBias, out);
}